// Round 3
// baseline (3339.030 us; speedup 1.0000x reference)
//
#include <hip/hip_runtime.h>

#define N_TOK   16384
#define CDIM    256
#define KDIM    512
#define VOCAB   8192

#define BM 64
#define BN 128
#define BK 32
#define LDK 36   // padded LDS stride in floats (32 would be a 16-way bank conflict)

__global__ __launch_bounds__(256) void vq_prep(const float* __restrict__ w,
                                               float* __restrict__ wnorm,
                                               float* __restrict__ counts,
                                               float* __restrict__ lossAcc) {
    int gid  = blockIdx.x * blockDim.x + threadIdx.x;
    int wave = gid >> 6;
    int lane = gid & 63;
    if (wave < VOCAB) {
        const float4* row = (const float4*)(w + (size_t)wave * KDIM);
        float s = 0.f;
        #pragma unroll
        for (int i = 0; i < 2; ++i) {
            float4 v = row[lane + 64 * i];
            s += v.x * v.x + v.y * v.y + v.z * v.z + v.w * v.w;
        }
        #pragma unroll
        for (int off = 32; off > 0; off >>= 1) s += __shfl_down(s, off);
        if (lane == 0) { wnorm[wave] = s; counts[wave] = 0.f; }
    }
    if (gid == 0) *lossAcc = 0.f;
}

__global__ __launch_bounds__(256) void vq_argmin(const float* __restrict__ zr,
                                                 const float* __restrict__ zi,
                                                 const float* __restrict__ w,
                                                 const float* __restrict__ wnorm,
                                                 int* __restrict__ idxOut,
                                                 float* __restrict__ counts) {
    __shared__ float zs[BM][LDK];
    __shared__ float wsm[BN][LDK];
    __shared__ float redV[BM][16];
    __shared__ int   redI[BM][16];

    const int tid = threadIdx.x;
    const int tx = tid & 15;   // code group
    const int ty = tid >> 4;   // token group
    const int tok0 = blockIdx.x * BM;

    float bestV[4];
    int   bestI[4];
    #pragma unroll
    for (int m = 0; m < 4; ++m) { bestV[m] = 3.4e38f; bestI[m] = 0x7fffffff; }

    for (int v0 = 0; v0 < VOCAB; v0 += BN) {
        float acc[4][8];
        #pragma unroll
        for (int m = 0; m < 4; ++m)
            #pragma unroll
            for (int n = 0; n < 8; ++n) acc[m][n] = 0.f;

        for (int k0 = 0; k0 < KDIM; k0 += BK) {
            __syncthreads();
            // stage z tile: BM x BK (a K-tile is entirely in real or imag half)
            const float* zsrc = (k0 < CDIM) ? (zr + k0) : (zi + (k0 - CDIM));
            #pragma unroll
            for (int r = 0; r < 2; ++r) {
                int f = tid + 256 * r;
                int row = f >> 3, c4 = f & 7;
                float4 v = *(const float4*)(zsrc + (size_t)(tok0 + row) * CDIM + c4 * 4);
                *(float4*)&zs[row][c4 * 4] = v;
            }
            // stage w tile: BN x BK
            #pragma unroll
            for (int r = 0; r < 4; ++r) {
                int f = tid + 256 * r;
                int row = f >> 3, c4 = f & 7;
                float4 v = *(const float4*)(w + (size_t)(v0 + row) * KDIM + k0 + c4 * 4);
                *(float4*)&wsm[row][c4 * 4] = v;
            }
            __syncthreads();
            #pragma unroll 2
            for (int kk = 0; kk < BK / 4; ++kk) {
                float4 a[4], b[8];
                #pragma unroll
                for (int m = 0; m < 4; ++m) a[m] = *(const float4*)&zs[ty * 4 + m][kk * 4];
                #pragma unroll
                for (int n = 0; n < 8; ++n) b[n] = *(const float4*)&wsm[n * 16 + tx][kk * 4];
                #pragma unroll
                for (int m = 0; m < 4; ++m)
                    #pragma unroll
                    for (int n = 0; n < 8; ++n)
                        acc[m][n] += a[m].x * b[n].x + a[m].y * b[n].y
                                   + a[m].z * b[n].z + a[m].w * b[n].w;
            }
        }
        // d2 = ||w||^2 - 2 z.w  (+||z||^2 constant per token, dropped)
        #pragma unroll
        for (int n = 0; n < 8; ++n) {
            int v = v0 + n * 16 + tx;   // ascending per thread -> strict < keeps first min
            float wn = wnorm[v];
            #pragma unroll
            for (int m = 0; m < 4; ++m) {
                float d = wn - 2.f * acc[m][n];
                if (d < bestV[m]) { bestV[m] = d; bestI[m] = v; }
            }
        }
    }
    #pragma unroll
    for (int m = 0; m < 4; ++m) {
        redV[ty * 4 + m][tx] = bestV[m];
        redI[ty * 4 + m][tx] = bestI[m];
    }
    __syncthreads();
    if (tid < BM) {
        float bv = redV[tid][0];
        int   bi = redI[tid][0];
        #pragma unroll
        for (int t = 1; t < 16; ++t) {
            float v = redV[tid][t];
            int   i = redI[tid][t];
            if (v < bv || (v == bv && i < bi)) { bv = v; bi = i; }  // first-min semantics
        }
        idxOut[tok0 + tid] = bi;
        atomicAdd(&counts[bi], 1.0f);
    }
}

// Computes the loss over ALL tokens; writes z_q only for tok < nTokOut
// (nTokOut derived from out_size on host so we never overrun d_out,
//  whichever way the harness counts complex elements).
__global__ __launch_bounds__(256) void vq_gather(const float* __restrict__ zr,
                                                 const float* __restrict__ zi,
                                                 const float* __restrict__ w,
                                                 const int* __restrict__ idx,
                                                 float* __restrict__ out,
                                                 float* __restrict__ lossAcc,
                                                 int nTokOut) {
    const int lane = threadIdx.x & 63;
    const int wv = threadIdx.x >> 6;
    const int tokBase = blockIdx.x * 16 + wv * 4;
    float s = 0.f;
    for (int t = 0; t < 4; ++t) {
        int tok = tokBase + t;
        int bi = idx[tok];
        const float4* wre = (const float4*)(w + (size_t)bi * KDIM);
        const float4* wim = (const float4*)(w + (size_t)bi * KDIM + CDIM);
        const float4* ar4 = (const float4*)(zr + (size_t)tok * CDIM);
        const float4* ai4 = (const float4*)(zi + (size_t)tok * CDIM);
        float4 qr = wre[lane], qi = wim[lane], ar = ar4[lane], ai = ai4[lane];
        float d;
        d = qr.x - ar.x; s += d * d;  d = qr.y - ar.y; s += d * d;
        d = qr.z - ar.z; s += d * d;  d = qr.w - ar.w; s += d * d;
        d = qi.x - ai.x; s += d * d;  d = qi.y - ai.y; s += d * d;
        d = qi.z - ai.z; s += d * d;  d = qi.w - ai.w; s += d * d;
        if (tok < nTokOut) {
            // complex64 memory layout: interleaved (real, imag)
            float4 o0 = make_float4(qr.x, qi.x, qr.y, qi.y);
            float4 o1 = make_float4(qr.z, qi.z, qr.w, qi.w);
            float4* ob = (float4*)(out + (size_t)tok * 2 * CDIM);
            ob[lane * 2]     = o0;
            ob[lane * 2 + 1] = o1;
        }
    }
    #pragma unroll
    for (int off = 32; off > 0; off >>= 1) s += __shfl_down(s, off);
    __shared__ float ls[4];
    if (lane == 0) ls[wv] = s;
    __syncthreads();
    if (threadIdx.x == 0) atomicAdd(lossAcc, ls[0] + ls[1] + ls[2] + ls[3]);
}

__global__ __launch_bounds__(256) void vq_final(const float* __restrict__ counts,
                                                const float* __restrict__ lossAcc,
                                                float* __restrict__ scal) {
    __shared__ float red[256];
    float s = 0.f;
    for (int i = threadIdx.x; i < VOCAB; i += 256) {
        float p = counts[i] * (1.0f / 16384.0f);
        s += p * logf(p + 1e-10f);
    }
    red[threadIdx.x] = s;
    __syncthreads();
    for (int off = 128; off > 0; off >>= 1) {
        if (threadIdx.x < off) red[threadIdx.x] += red[threadIdx.x + off];
        __syncthreads();
    }
    if (threadIdx.x == 0) {
        // vq_loss = codebook + 0.25*commitment = 1.25 * S / (N*2*CDIM)
        scal[0] = lossAcc[0] * (1.25f / 8388608.0f);
        scal[1] = expf(-red[0]);
    }
}

extern "C" void kernel_launch(void* const* d_in, const int* in_sizes, int n_in,
                              void* d_out, int out_size, void* d_ws, size_t ws_size,
                              hipStream_t stream) {
    const float* zr = (const float*)d_in[0];
    const float* zi = (const float*)d_in[1];
    const float* w  = (const float*)d_in[2];
    float* out = (float*)d_out;
    float* fws = (float*)d_ws;
    float* wnorm   = fws;                 // [VOCAB]
    float* counts  = fws + VOCAB;         // [VOCAB]
    float* lossAcc = fws + 2 * VOCAB;     // [1]
    int*   idx     = (int*)(fws + 2 * VOCAB + 16);  // [N_TOK]

    // Clamp z_q writes to the actual d_out capacity: out_size may count the
    // complex output as complex elements (N*DIM) or as float pairs (N*2*DIM).
    int nTokOut = (out_size - 2) / (2 * CDIM);
    if (nTokOut > N_TOK) nTokOut = N_TOK;

    vq_prep<<<VOCAB * 64 / 256, 256, 0, stream>>>(w, wnorm, counts, lossAcc);
    vq_argmin<<<N_TOK / BM, 256, 0, stream>>>(zr, zi, w, wnorm, idx, counts);
    vq_gather<<<N_TOK / 16, 256, 0, stream>>>(zr, zi, w, idx, out, lossAcc, nTokOut);
    vq_final<<<1, 256, 0, stream>>>(counts, lossAcc, out + (out_size - 2));
}

// Round 4
// 475.027 us; speedup vs baseline: 7.0291x; 7.0291x over previous
//
#include <hip/hip_runtime.h>

#define N_TOK   16384
#define CDIM    256
#define KDIM    512
#define VOCAB   8192

#define SLICES  8
#define SL_V    (VOCAB / SLICES)   // 1024 codes per slice
#define BMM     64                 // tokens per block
#define BNN     128                // codes per N-tile
#define BKK     64                 // K per step

typedef __attribute__((ext_vector_type(8))) short short8v;
typedef __attribute__((ext_vector_type(4))) float f32x4;

typedef const __attribute__((address_space(1))) unsigned int* gp_t;
typedef __attribute__((address_space(3))) unsigned int* lp_t;
__device__ __forceinline__ void gl16(const void* g, void* l) {
    // async global->LDS, 16B per lane; LDS dest = wave-uniform base + lane*16
    __builtin_amdgcn_global_load_lds((gp_t)g, (lp_t)l, 16, 0, 0);
}

__device__ __forceinline__ unsigned int bf2(float a, float b) {
    unsigned int ua = __float_as_uint(a); ua = (ua + 0x7FFF + ((ua >> 16) & 1)) >> 16;
    unsigned int ub = __float_as_uint(b); ub = (ub + 0x7FFF + ((ub >> 16) & 1)) >> 16;
    return (ub << 16) | ua;
}

// ---- z concat + fp32->bf16 convert: zc[tok][0:256]=re, [256:512]=im ----
__global__ __launch_bounds__(256) void vq_zconv(const float* __restrict__ zr,
                                                const float* __restrict__ zi,
                                                unsigned short* __restrict__ zc) {
    int t = blockIdx.x * 256 + threadIdx.x;
    int e = t * 8;                       // 8 bf16 per thread
    int tok = e >> 9, c = e & 511;
    const float* src = (c < CDIM) ? (zr + (size_t)tok * CDIM + c)
                                  : (zi + (size_t)tok * CDIM + (c - CDIM));
    float4 x = ((const float4*)src)[0];
    float4 y = ((const float4*)src)[1];
    uint4 o = make_uint4(bf2(x.x, x.y), bf2(x.z, x.w), bf2(y.x, y.y), bf2(y.z, y.w));
    *(uint4*)(zc + e) = o;
}

// ---- w fp32->bf16 + exact fp32 ||w||^2, zero counts/lossAcc ----
__global__ __launch_bounds__(256) void vq_wconv(const float* __restrict__ w,
                                                unsigned short* __restrict__ wb,
                                                float* __restrict__ wnorm,
                                                float* __restrict__ counts,
                                                float* __restrict__ lossAcc) {
    int gid = blockIdx.x * 256 + threadIdx.x;
    int row = gid >> 6, l = gid & 63;    // one wave per codebook row
    const float* src = w + (size_t)row * KDIM + l * 8;
    float4 x = ((const float4*)src)[0];
    float4 y = ((const float4*)src)[1];
    float s = x.x*x.x + x.y*x.y + x.z*x.z + x.w*x.w
            + y.x*y.x + y.y*y.y + y.z*y.z + y.w*y.w;
    uint4 o = make_uint4(bf2(x.x, x.y), bf2(x.z, x.w), bf2(y.x, y.y), bf2(y.z, y.w));
    *(uint4*)(wb + (size_t)row * KDIM + l * 8) = o;
    #pragma unroll
    for (int off = 32; off > 0; off >>= 1) s += __shfl_down(s, off);
    if (l == 0) { wnorm[row] = s; counts[row] = 0.f; }
    if (gid == 0) *lossAcc = 0.f;
}

// ---- fused bf16-MFMA distance GEMM + per-slice argmin ----
__global__ __launch_bounds__(256) void vq_argmin_mfma(const unsigned short* __restrict__ zc,
                                                      const unsigned short* __restrict__ wb,
                                                      const float* __restrict__ wnorm,
                                                      float* __restrict__ sbV,
                                                      int* __restrict__ sbI) {
    __shared__ unsigned short Asm[2][BMM * BKK];   // [buf][row*64 + k]
    __shared__ unsigned short Bsm[2][BNN * BKK];
    __shared__ float sV[2][BMM];
    __shared__ int   sI[2][BMM];
    __shared__ float runV[BMM];
    __shared__ int   runI[BMM];

    const int tid = threadIdx.x;
    const int l   = tid & 63, wv = tid >> 6;
    const int wm  = wv >> 1,  wn = wv & 1;       // wave tile: rows wm*32, cols wn*64
    const int slice = blockIdx.x & (SLICES - 1); // -> XCD (round-robin dispatch)
    const int tok0  = (blockIdx.x >> 3) * BMM;
    const int code0 = slice * SL_V;

    if (tid < BMM) { runV[tid] = 3.4e38f; runI[tid] = 0; }

    const int l15 = l & 15, lhi = l >> 4;

    for (int v0 = 0; v0 < SL_V; v0 += BNN) {
        f32x4 acc[2][4] = {};

        // ---- staging helper: A (2x16B/thread), B (4x16B/thread) ----
        auto STAGE = [&](int buf, int k0) {
            #pragma unroll
            for (int i = 0; i < 2; ++i) {
                int e = i * 2048 + tid * 8;      // elem within A tile
                int r = e >> 6, c = e & 63;
                gl16(zc + (size_t)(tok0 + r) * KDIM + k0 + c,
                     (void*)&Asm[buf][i * 2048 + wv * 512]);
            }
            #pragma unroll
            for (int i = 0; i < 4; ++i) {
                int e = i * 2048 + tid * 8;      // elem within B tile
                int r = e >> 6, c = e & 63;
                gl16(wb + (size_t)(code0 + v0 + r) * KDIM + k0 + c,
                     (void*)&Bsm[buf][i * 2048 + wv * 512]);
            }
        };

        STAGE(0, 0);
        __syncthreads();
        for (int ks = 0; ks < KDIM / BKK; ++ks) {
            int cur = ks & 1;
            if (ks < KDIM / BKK - 1) STAGE(cur ^ 1, (ks + 1) * BKK);
            #pragma unroll
            for (int c = 0; c < 2; ++c) {        // BK=64 -> two MFMA-K chunks
                short8v a[2], b[4];
                #pragma unroll
                for (int m = 0; m < 2; ++m)
                    a[m] = *(const short8v*)&Asm[cur][(wm * 32 + m * 16 + l15) * 64 + c * 32 + lhi * 8];
                #pragma unroll
                for (int n = 0; n < 4; ++n)
                    b[n] = *(const short8v*)&Bsm[cur][(wn * 64 + n * 16 + l15) * 64 + c * 32 + lhi * 8];
                #pragma unroll
                for (int m = 0; m < 2; ++m)
                    #pragma unroll
                    for (int n = 0; n < 4; ++n)
                        acc[m][n] = __builtin_amdgcn_mfma_f32_16x16x32_bf16(a[m], b[n], acc[m][n], 0, 0, 0);
            }
            __syncthreads();   // drains vmcnt (staging) + lgkmcnt (ds_reads)
        }

        // ---- epilogue: d2' = ||w||^2 - 2 z.w ; per-token argmin ----
        const int ccolbase = code0 + v0 + wn * 64 + l15;
        float wn4[4];
        #pragma unroll
        for (int n = 0; n < 4; ++n) wn4[n] = wnorm[ccolbase + n * 16];

        #pragma unroll
        for (int m = 0; m < 2; ++m) {
            #pragma unroll
            for (int r = 0; r < 4; ++r) {
                float best = 3.4e38f; int bi = 0x7fffffff;
                #pragma unroll
                for (int n = 0; n < 4; ++n) {
                    float d = wn4[n] - 2.f * acc[m][n][r];
                    int ci = ccolbase + n * 16;
                    if (d < best) { best = d; bi = ci; }   // n ascending -> first-min
                }
                #pragma unroll
                for (int mk = 1; mk < 16; mk <<= 1) {
                    float ov = __shfl_xor(best, mk);
                    int   oi = __shfl_xor(bi, mk);
                    if (ov < best || (ov == best && oi < bi)) { best = ov; bi = oi; }
                }
                if (l15 == 0) {
                    int row = wm * 32 + m * 16 + lhi * 4 + r;
                    sV[wn][row] = best; sI[wn][row] = bi;
                }
            }
        }
        __syncthreads();
        if (tid < BMM) {
            float va = sV[0][tid]; int ia = sI[0][tid];
            float vb = sV[1][tid]; int ib = sI[1][tid];
            if (vb < va || (vb == va && ib < ia)) { va = vb; ia = ib; }
            if (va < runV[tid] || (va == runV[tid] && ia < runI[tid])) { runV[tid] = va; runI[tid] = ia; }
        }
        // next write to sV/sI is after the next N-tile's K-loop barriers
    }

    if (tid < BMM) {
        sbV[slice * N_TOK + tok0 + tid] = runV[tid];
        sbI[slice * N_TOK + tok0 + tid] = runI[tid];
    }
}

// ---- merge 8 slice-results -> final index + histogram ----
__global__ __launch_bounds__(256) void vq_reduce(const float* __restrict__ sbV,
                                                 const int* __restrict__ sbI,
                                                 int* __restrict__ idx,
                                                 float* __restrict__ counts) {
    int t = blockIdx.x * 256 + threadIdx.x;
    float bv = sbV[t]; int bi = sbI[t];
    #pragma unroll
    for (int s = 1; s < SLICES; ++s) {
        float v = sbV[s * N_TOK + t];
        int   i = sbI[s * N_TOK + t];
        if (v < bv || (v == bv && i < bi)) { bv = v; bi = i; }
    }
    idx[t] = bi;
    atomicAdd(&counts[bi], 1.0f);
}

// ---- gather z_q (interleaved complex), block-reduced squared error ----
__global__ __launch_bounds__(256) void vq_gather(const float* __restrict__ zr,
                                                 const float* __restrict__ zi,
                                                 const float* __restrict__ w,
                                                 const int* __restrict__ idx,
                                                 float* __restrict__ out,
                                                 float* __restrict__ lossAcc,
                                                 int nTokOut) {
    const int lane = threadIdx.x & 63;
    const int wv = threadIdx.x >> 6;
    const int tokBase = blockIdx.x * 16 + wv * 4;
    float s = 0.f;
    for (int t = 0; t < 4; ++t) {
        int tok = tokBase + t;
        int bi = idx[tok];
        const float4* wre = (const float4*)(w + (size_t)bi * KDIM);
        const float4* wim = (const float4*)(w + (size_t)bi * KDIM + CDIM);
        const float4* ar4 = (const float4*)(zr + (size_t)tok * CDIM);
        const float4* ai4 = (const float4*)(zi + (size_t)tok * CDIM);
        float4 qr = wre[lane], qi = wim[lane], ar = ar4[lane], ai = ai4[lane];
        float d;
        d = qr.x - ar.x; s += d * d;  d = qr.y - ar.y; s += d * d;
        d = qr.z - ar.z; s += d * d;  d = qr.w - ar.w; s += d * d;
        d = qi.x - ai.x; s += d * d;  d = qi.y - ai.y; s += d * d;
        d = qi.z - ai.z; s += d * d;  d = qi.w - ai.w; s += d * d;
        if (tok < nTokOut) {
            float4 o0 = make_float4(qr.x, qi.x, qr.y, qi.y);
            float4 o1 = make_float4(qr.z, qi.z, qr.w, qi.w);
            float4* ob = (float4*)(out + (size_t)tok * 2 * CDIM);
            ob[lane * 2]     = o0;
            ob[lane * 2 + 1] = o1;
        }
    }
    #pragma unroll
    for (int off = 32; off > 0; off >>= 1) s += __shfl_down(s, off);
    __shared__ float ls[4];
    if (lane == 0) ls[wv] = s;
    __syncthreads();
    if (threadIdx.x == 0) atomicAdd(lossAcc, ls[0] + ls[1] + ls[2] + ls[3]);
}

__global__ __launch_bounds__(256) void vq_final(const float* __restrict__ counts,
                                                const float* __restrict__ lossAcc,
                                                float* __restrict__ scal) {
    __shared__ float red[256];
    float s = 0.f;
    for (int i = threadIdx.x; i < VOCAB; i += 256) {
        float p = counts[i] * (1.0f / 16384.0f);
        s += p * logf(p + 1e-10f);
    }
    red[threadIdx.x] = s;
    __syncthreads();
    for (int off = 128; off > 0; off >>= 1) {
        if (threadIdx.x < off) red[threadIdx.x] += red[threadIdx.x + off];
        __syncthreads();
    }
    if (threadIdx.x == 0) {
        scal[0] = lossAcc[0] * (1.25f / 8388608.0f);   // 1.25 * S / (N*2*CDIM)
        scal[1] = expf(-red[0]);
    }
}

extern "C" void kernel_launch(void* const* d_in, const int* in_sizes, int n_in,
                              void* d_out, int out_size, void* d_ws, size_t ws_size,
                              hipStream_t stream) {
    const float* zr = (const float*)d_in[0];
    const float* zi = (const float*)d_in[1];
    const float* w  = (const float*)d_in[2];
    float* out = (float*)d_out;
    float* fws = (float*)d_ws;

    // ws layout (float offsets; ~26.3 MB total)
    float* wnorm   = fws;                                  // [8192]
    float* counts  = fws + 8192;                           // [8192]
    float* lossAcc = fws + 16384;                          // [1] (+pad)
    int*   idx     = (int*)(fws + 16400);                  // [16384]
    float* sbV     = fws + 32784;                          // [8*16384]
    int*   sbI     = (int*)(fws + 163856);                 // [8*16384]
    unsigned short* zc = (unsigned short*)(fws + 294928);  // [16384*512] bf16
    unsigned short* wb = (unsigned short*)(fws + 294928 + 4194304); // [8192*512] bf16

    int nTokOut = (out_size - 2) / (2 * CDIM);
    if (nTokOut > N_TOK) nTokOut = N_TOK;

    vq_zconv<<<4096, 256, 0, stream>>>(zr, zi, zc);
    vq_wconv<<<2048, 256, 0, stream>>>(w, wb, wnorm, counts, lossAcc);
    vq_argmin_mfma<<<(N_TOK / BMM) * SLICES, 256, 0, stream>>>(zc, wb, wnorm, sbV, sbI);
    vq_reduce<<<N_TOK / 256, 256, 0, stream>>>(sbV, sbI, idx, counts);
    vq_gather<<<N_TOK / 16, 256, 0, stream>>>(zr, zi, w, idx, out, lossAcc, nTokOut);
    vq_final<<<1, 256, 0, stream>>>(counts, lossAcc, out + (out_size - 2));
}

// Round 6
// 435.152 us; speedup vs baseline: 7.6733x; 1.0916x over previous
//
#include <hip/hip_runtime.h>

#define N_TOK   16384
#define CDIM    256
#define KDIM    512
#define VOCAB   8192

#define SLICES  8
#define SL_V    (VOCAB / SLICES)   // 1024 codes per slice
#define BMM     64                 // tokens per block
#define BNN     128                // codes per N-tile
#define BKK     64                 // K per step

typedef __attribute__((ext_vector_type(8))) short short8v;
typedef __attribute__((ext_vector_type(4))) float f32x4;

typedef const __attribute__((address_space(1))) unsigned int* gp_t;
typedef __attribute__((address_space(3))) unsigned int* lp_t;
__device__ __forceinline__ void gl16(const void* g, void* l) {
    // async global->LDS, 16B per lane; LDS dest = wave-uniform base + lane*16
    __builtin_amdgcn_global_load_lds((gp_t)g, (lp_t)l, 16, 0, 0);
}

__device__ __forceinline__ unsigned int bf2(float a, float b) {
    unsigned int ua = __float_as_uint(a); ua = (ua + 0x7FFF + ((ua >> 16) & 1)) >> 16;
    unsigned int ub = __float_as_uint(b); ub = (ub + 0x7FFF + ((ub >> 16) & 1)) >> 16;
    return (ub << 16) | ua;
}

// ---- z concat + fp32->bf16 convert: zc[tok][0:256]=re, [256:512]=im ----
__global__ __launch_bounds__(256) void vq_zconv(const float* __restrict__ zr,
                                                const float* __restrict__ zi,
                                                unsigned short* __restrict__ zc) {
    int t = blockIdx.x * 256 + threadIdx.x;
    int e = t * 8;                       // 8 bf16 per thread
    int tok = e >> 9, c = e & 511;
    const float* src = (c < CDIM) ? (zr + (size_t)tok * CDIM + c)
                                  : (zi + (size_t)tok * CDIM + (c - CDIM));
    float4 x = ((const float4*)src)[0];
    float4 y = ((const float4*)src)[1];
    uint4 o = make_uint4(bf2(x.x, x.y), bf2(x.z, x.w), bf2(y.x, y.y), bf2(y.z, y.w));
    *(uint4*)(zc + e) = o;
}

// ---- w fp32->bf16 + exact fp32 ||w||^2, zero counts/lossAcc ----
__global__ __launch_bounds__(256) void vq_wconv(const float* __restrict__ w,
                                                unsigned short* __restrict__ wb,
                                                float* __restrict__ wnorm,
                                                float* __restrict__ counts,
                                                float* __restrict__ lossAcc) {
    int gid = blockIdx.x * 256 + threadIdx.x;
    int row = gid >> 6, l = gid & 63;    // one wave per codebook row
    const float* src = w + (size_t)row * KDIM + l * 8;
    float4 x = ((const float4*)src)[0];
    float4 y = ((const float4*)src)[1];
    float s = x.x*x.x + x.y*x.y + x.z*x.z + x.w*x.w
            + y.x*y.x + y.y*y.y + y.z*y.z + y.w*y.w;
    uint4 o = make_uint4(bf2(x.x, x.y), bf2(x.z, x.w), bf2(y.x, y.y), bf2(y.z, y.w));
    *(uint4*)(wb + (size_t)row * KDIM + l * 8) = o;
    #pragma unroll
    for (int off = 32; off > 0; off >>= 1) s += __shfl_down(s, off);
    if (l == 0) { wnorm[row] = s; counts[row] = 0.f; }
    if (gid == 0) *lossAcc = 0.f;
}

// ---- fused bf16-MFMA distance GEMM + per-slice argmin ----
// LDS tiles are XOR-swizzled (T2): logical element (row, 16B-slot j) is stored
// at physical slot j^(row&7). Staging achieves this with LINEAR LDS writes by
// pre-swizzling the per-lane GLOBAL source address (rule #21 / m173 pattern);
// fragment ds_reads apply the same XOR. Breaks the 16-way conflict of the
// 128B-stride row-major tile (was SQ_LDS_BANK_CONFLICT=7.55e7, 33% of cycles).
__global__ __launch_bounds__(256) void vq_argmin_mfma(const unsigned short* __restrict__ zc,
                                                      const unsigned short* __restrict__ wb,
                                                      const float* __restrict__ wnorm,
                                                      float* __restrict__ sbV,
                                                      int* __restrict__ sbI) {
    __shared__ unsigned short Asm[2][BMM * BKK];   // [buf][row*64 + swz(col)]
    __shared__ unsigned short Bsm[2][BNN * BKK];
    __shared__ float sV[2][BMM];
    __shared__ int   sI[2][BMM];
    __shared__ float runV[BMM];
    __shared__ int   runI[BMM];

    const int tid = threadIdx.x;
    const int l   = tid & 63, wv = tid >> 6;
    const int wm  = wv >> 1,  wn = wv & 1;       // wave tile: rows wm*32, cols wn*64
    const int slice = blockIdx.x & (SLICES - 1); // -> XCD (round-robin dispatch)
    const int tok0  = (blockIdx.x >> 3) * BMM;
    const int code0 = slice * SL_V;

    if (tid < BMM) { runV[tid] = 3.4e38f; runI[tid] = 0; }

    const int l15 = l & 15, lhi = l >> 4;

    for (int v0 = 0; v0 < SL_V; v0 += BNN) {
        f32x4 acc[2][4] = {};

        // ---- staging: A (2x16B/thread), B (4x16B/thread), source pre-swizzled ----
        auto STAGE = [&](int buf, int k0) {
            #pragma unroll
            for (int i = 0; i < 2; ++i) {
                int e = i * 2048 + tid * 8;
                int r = e >> 6;                              // tile row; r&7 == (tid>>3)&7
                int cs = (((tid & 7) ^ (r & 7)) * 8);        // swizzled 8-elem slot
                gl16(zc + (size_t)(tok0 + r) * KDIM + k0 + cs,
                     (void*)&Asm[buf][i * 2048 + wv * 512]);
            }
            #pragma unroll
            for (int i = 0; i < 4; ++i) {
                int e = i * 2048 + tid * 8;
                int r = e >> 6;
                int cs = (((tid & 7) ^ (r & 7)) * 8);
                gl16(wb + (size_t)(code0 + v0 + r) * KDIM + k0 + cs,
                     (void*)&Bsm[buf][i * 2048 + wv * 512]);
            }
        };

        STAGE(0, 0);
        __syncthreads();
        for (int ks = 0; ks < KDIM / BKK; ++ks) {
            int cur = ks & 1;
            if (ks < KDIM / BKK - 1) STAGE(cur ^ 1, (ks + 1) * BKK);
            #pragma unroll
            for (int c = 0; c < 2; ++c) {        // BK=64 -> two MFMA-K chunks
                short8v a[2], b[4];
                #pragma unroll
                for (int m = 0; m < 2; ++m) {
                    int rowA = wm * 32 + m * 16 + l15;
                    a[m] = *(const short8v*)&Asm[cur][rowA * 64 + (((c * 4 + lhi) ^ (rowA & 7)) * 8)];
                }
                #pragma unroll
                for (int n = 0; n < 4; ++n) {
                    int rowB = wn * 64 + n * 16 + l15;
                    b[n] = *(const short8v*)&Bsm[cur][rowB * 64 + (((c * 4 + lhi) ^ (rowB & 7)) * 8)];
                }
                #pragma unroll
                for (int m = 0; m < 2; ++m)
                    #pragma unroll
                    for (int n = 0; n < 4; ++n)
                        acc[m][n] = __builtin_amdgcn_mfma_f32_16x16x32_bf16(a[m], b[n], acc[m][n], 0, 0, 0);
            }
            __syncthreads();   // drains vmcnt (staging) + lgkmcnt (ds_reads)
        }

        // ---- epilogue: d2' = ||w||^2 - 2 z.w ; per-token argmin ----
        const int ccolbase = code0 + v0 + wn * 64 + l15;
        float wn4[4];
        #pragma unroll
        for (int n = 0; n < 4; ++n) wn4[n] = wnorm[ccolbase + n * 16];

        #pragma unroll
        for (int m = 0; m < 2; ++m) {
            #pragma unroll
            for (int r = 0; r < 4; ++r) {
                float best = 3.4e38f; int bi = 0x7fffffff;
                #pragma unroll
                for (int n = 0; n < 4; ++n) {
                    float d = wn4[n] - 2.f * acc[m][n][r];
                    int ci = ccolbase + n * 16;
                    if (d < best) { best = d; bi = ci; }   // n ascending -> first-min
                }
                #pragma unroll
                for (int mk = 1; mk < 16; mk <<= 1) {
                    float ov = __shfl_xor(best, mk);
                    int   oi = __shfl_xor(bi, mk);
                    if (ov < best || (ov == best && oi < bi)) { best = ov; bi = oi; }
                }
                if (l15 == 0) {
                    int row = wm * 32 + m * 16 + lhi * 4 + r;
                    sV[wn][row] = best; sI[wn][row] = bi;
                }
            }
        }
        __syncthreads();
        if (tid < BMM) {
            float va = sV[0][tid]; int ia = sI[0][tid];
            float vb = sV[1][tid]; int ib = sI[1][tid];
            if (vb < va || (vb == va && ib < ia)) { va = vb; ia = ib; }
            if (va < runV[tid] || (va == runV[tid] && ia < runI[tid])) { runV[tid] = va; runI[tid] = ia; }
        }
        // next write to sV/sI is after the next N-tile's K-loop barriers
    }

    if (tid < BMM) {
        sbV[slice * N_TOK + tok0 + tid] = runV[tid];
        sbI[slice * N_TOK + tok0 + tid] = runI[tid];
    }
}

// ---- merge 8 slice-results -> final index + histogram ----
__global__ __launch_bounds__(256) void vq_reduce(const float* __restrict__ sbV,
                                                 const int* __restrict__ sbI,
                                                 int* __restrict__ idx,
                                                 float* __restrict__ counts) {
    int t = blockIdx.x * 256 + threadIdx.x;
    float bv = sbV[t]; int bi = sbI[t];
    #pragma unroll
    for (int s = 1; s < SLICES; ++s) {
        float v = sbV[s * N_TOK + t];
        int   i = sbI[s * N_TOK + t];
        if (v < bv || (v == bv && i < bi)) { bv = v; bi = i; }
    }
    idx[t] = bi;
    atomicAdd(&counts[bi], 1.0f);
}

// ---- gather z_q (interleaved complex), block-reduced squared error ----
__global__ __launch_bounds__(256) void vq_gather(const float* __restrict__ zr,
                                                 const float* __restrict__ zi,
                                                 const float* __restrict__ w,
                                                 const int* __restrict__ idx,
                                                 float* __restrict__ out,
                                                 float* __restrict__ lossAcc,
                                                 int nTokOut) {
    const int lane = threadIdx.x & 63;
    const int wv = threadIdx.x >> 6;
    const int tokBase = blockIdx.x * 16 + wv * 4;
    float s = 0.f;
    for (int t = 0; t < 4; ++t) {
        int tok = tokBase + t;
        int bi = idx[tok];
        const float4* wre = (const float4*)(w + (size_t)bi * KDIM);
        const float4* wim = (const float4*)(w + (size_t)bi * KDIM + CDIM);
        const float4* ar4 = (const float4*)(zr + (size_t)tok * CDIM);
        const float4* ai4 = (const float4*)(zi + (size_t)tok * CDIM);
        float4 qr = wre[lane], qi = wim[lane], ar = ar4[lane], ai = ai4[lane];
        float d;
        d = qr.x - ar.x; s += d * d;  d = qr.y - ar.y; s += d * d;
        d = qr.z - ar.z; s += d * d;  d = qr.w - ar.w; s += d * d;
        d = qi.x - ai.x; s += d * d;  d = qi.y - ai.y; s += d * d;
        d = qi.z - ai.z; s += d * d;  d = qi.w - ai.w; s += d * d;
        if (tok < nTokOut) {
            float4 o0 = make_float4(qr.x, qi.x, qr.y, qi.y);
            float4 o1 = make_float4(qr.z, qi.z, qr.w, qi.w);
            float4* ob = (float4*)(out + (size_t)tok * 2 * CDIM);
            ob[lane * 2]     = o0;
            ob[lane * 2 + 1] = o1;
        }
    }
    #pragma unroll
    for (int off = 32; off > 0; off >>= 1) s += __shfl_down(s, off);
    __shared__ float ls[4];
    if (lane == 0) ls[wv] = s;
    __syncthreads();
    if (threadIdx.x == 0) atomicAdd(lossAcc, ls[0] + ls[1] + ls[2] + ls[3]);
}

__global__ __launch_bounds__(256) void vq_final(const float* __restrict__ counts,
                                                const float* __restrict__ lossAcc,
                                                float* __restrict__ scal) {
    __shared__ float red[256];
    float s = 0.f;
    for (int i = threadIdx.x; i < VOCAB; i += 256) {
        float p = counts[i] * (1.0f / 16384.0f);
        s += p * logf(p + 1e-10f);
    }
    red[threadIdx.x] = s;
    __syncthreads();
    for (int off = 128; off > 0; off >>= 1) {
        if (threadIdx.x < off) red[threadIdx.x] += red[threadIdx.x + off];
        __syncthreads();
    }
    if (threadIdx.x == 0) {
        scal[0] = lossAcc[0] * (1.25f / 8388608.0f);   // 1.25 * S / (N*2*CDIM)
        scal[1] = expf(-red[0]);
    }
}

extern "C" void kernel_launch(void* const* d_in, const int* in_sizes, int n_in,
                              void* d_out, int out_size, void* d_ws, size_t ws_size,
                              hipStream_t stream) {
    const float* zr = (const float*)d_in[0];
    const float* zi = (const float*)d_in[1];
    const float* w  = (const float*)d_in[2];
    float* out = (float*)d_out;
    float* fws = (float*)d_ws;

    // ws layout (float offsets; ~26.3 MB total)
    float* wnorm   = fws;                                  // [8192]
    float* counts  = fws + 8192;                           // [8192]
    float* lossAcc = fws + 16384;                          // [1] (+pad)
    int*   idx     = (int*)(fws + 16400);                  // [16384]
    float* sbV     = fws + 32784;                          // [8*16384]
    int*   sbI     = (int*)(fws + 163856);                 // [8*16384]
    unsigned short* zc = (unsigned short*)(fws + 294928);  // [16384*512] bf16
    unsigned short* wb = (unsigned short*)(fws + 294928 + 4194304); // [8192*512] bf16

    int nTokOut = (out_size - 2) / (2 * CDIM);
    if (nTokOut > N_TOK) nTokOut = N_TOK;

    vq_zconv<<<4096, 256, 0, stream>>>(zr, zi, zc);
    vq_wconv<<<2048, 256, 0, stream>>>(w, wb, wnorm, counts, lossAcc);
    vq_argmin_mfma<<<(N_TOK / BMM) * SLICES, 256, 0, stream>>>(zc, wb, wnorm, sbV, sbI);
    vq_reduce<<<N_TOK / 256, 256, 0, stream>>>(sbV, sbI, idx, counts);
    vq_gather<<<N_TOK / 16, 256, 0, stream>>>(zr, zi, w, idx, out, lossAcc, nTokOut);
    vq_final<<<1, 256, 0, stream>>>(counts, lossAcc, out + (out_size - 2));
}

// Round 9
// 434.721 us; speedup vs baseline: 7.6809x; 1.0010x over previous
//
#include <hip/hip_runtime.h>

#define N_TOK   16384
#define CDIM    256
#define KDIM    512
#define VOCAB   8192

#define SLICES  8
#define SL_V    (VOCAB / SLICES)   // 1024 codes per slice
#define BMM     64                 // tokens per block
#define BNN     128                // codes per N-tile
#define BKK     64                 // K per step
#define NKS     (KDIM / BKK)       // 8 K-steps

typedef __attribute__((ext_vector_type(8))) short short8v;
typedef __attribute__((ext_vector_type(4))) float f32x4;

typedef const __attribute__((address_space(1))) unsigned int* gp_t;
typedef __attribute__((address_space(3))) unsigned int* lp_t;
__device__ __forceinline__ void gl16(const void* g, void* l) {
    // async global->LDS, 16B per lane; LDS dest = wave-uniform base + lane*16
    __builtin_amdgcn_global_load_lds((gp_t)g, (lp_t)l, 16, 0, 0);
}

__device__ __forceinline__ unsigned int bf2(float a, float b) {
    unsigned int ua = __float_as_uint(a); ua = (ua + 0x7FFF + ((ua >> 16) & 1)) >> 16;
    unsigned int ub = __float_as_uint(b); ub = (ub + 0x7FFF + ((ub >> 16) & 1)) >> 16;
    return (ub << 16) | ua;
}

// ---- z concat + fp32->bf16 convert: zc[tok][0:256]=re, [256:512]=im ----
__global__ __launch_bounds__(256) void vq_zconv(const float* __restrict__ zr,
                                                const float* __restrict__ zi,
                                                unsigned short* __restrict__ zc) {
    int t = blockIdx.x * 256 + threadIdx.x;
    int e = t * 8;                       // 8 bf16 per thread
    int tok = e >> 9, c = e & 511;
    const float* src = (c < CDIM) ? (zr + (size_t)tok * CDIM + c)
                                  : (zi + (size_t)tok * CDIM + (c - CDIM));
    float4 x = ((const float4*)src)[0];
    float4 y = ((const float4*)src)[1];
    uint4 o = make_uint4(bf2(x.x, x.y), bf2(x.z, x.w), bf2(y.x, y.y), bf2(y.z, y.w));
    *(uint4*)(zc + e) = o;
}

// ---- w fp32->bf16 + exact fp32 ||w||^2, zero counts/lossAcc ----
__global__ __launch_bounds__(256) void vq_wconv(const float* __restrict__ w,
                                                unsigned short* __restrict__ wb,
                                                float* __restrict__ wnorm,
                                                float* __restrict__ counts,
                                                float* __restrict__ lossAcc) {
    int gid = blockIdx.x * 256 + threadIdx.x;
    int row = gid >> 6, l = gid & 63;    // one wave per codebook row
    const float* src = w + (size_t)row * KDIM + l * 8;
    float4 x = ((const float4*)src)[0];
    float4 y = ((const float4*)src)[1];
    float s = x.x*x.x + x.y*x.y + x.z*x.z + x.w*x.w
            + y.x*y.x + y.y*y.y + y.z*y.z + y.w*y.w;
    uint4 o = make_uint4(bf2(x.x, x.y), bf2(x.z, x.w), bf2(y.x, y.y), bf2(y.z, y.w));
    *(uint4*)(wb + (size_t)row * KDIM + l * 8) = o;
    #pragma unroll
    for (int off = 32; off > 0; off >>= 1) s += __shfl_down(s, off);
    if (l == 0) { wnorm[row] = s; counts[row] = 0.f; }
    if (gid == 0) *lossAcc = 0.f;
}

// ---- fused bf16-MFMA distance GEMM + per-slice argmin ----
// T2: LDS tiles XOR-swizzled via pre-swizzled GLOBAL source (linear LDS dest,
// rule #21); ds_reads apply the same XOR. Bank conflicts: 7.55e7 -> 0 (r6).
// T4: 3-buffer pipeline with counted s_waitcnt vmcnt(6) + raw s_barrier —
// tile ks+2's staging loads stay in flight across the barrier, so each tile
// has ~2 iterations of compute to cover its load latency (was: full vmcnt(0)
// drain per K-step via __syncthreads = exposed L2/L3 latency every step).
__global__ __launch_bounds__(256) void vq_argmin_mfma(const unsigned short* __restrict__ zc,
                                                      const unsigned short* __restrict__ wb,
                                                      const float* __restrict__ wnorm,
                                                      float* __restrict__ sbV,
                                                      int* __restrict__ sbI) {
    __shared__ unsigned short Asm[3][BMM * BKK];   // [buf][row*64 + swz(col)]
    __shared__ unsigned short Bsm[3][BNN * BKK];
    __shared__ float sV[2][BMM];
    __shared__ int   sI[2][BMM];
    __shared__ float runV[BMM];
    __shared__ int   runI[BMM];

    const int tid = threadIdx.x;
    const int l   = tid & 63, wv = tid >> 6;
    const int wm  = wv >> 1,  wn = wv & 1;       // wave tile: rows wm*32, cols wn*64
    const int slice = blockIdx.x & (SLICES - 1); // -> XCD (round-robin dispatch)
    const int tok0  = (blockIdx.x >> 3) * BMM;
    const int code0 = slice * SL_V;

    if (tid < BMM) { runV[tid] = 3.4e38f; runI[tid] = 0; }

    const int l15 = l & 15, lhi = l >> 4;

    for (int v0 = 0; v0 < SL_V; v0 += BNN) {
        f32x4 acc[2][4] = {};

        // ---- staging: A (2x16B/thread), B (4x16B/thread), source pre-swizzled ----
        auto STAGE = [&](int buf, int k0) {
            #pragma unroll
            for (int i = 0; i < 2; ++i) {
                int e = i * 2048 + tid * 8;
                int r = e >> 6;                              // tile row; r&7 == (tid>>3)&7
                int cs = (((tid & 7) ^ (r & 7)) * 8);        // swizzled 8-elem slot
                gl16(zc + (size_t)(tok0 + r) * KDIM + k0 + cs,
                     (void*)&Asm[buf][i * 2048 + wv * 512]);
            }
            #pragma unroll
            for (int i = 0; i < 4; ++i) {
                int e = i * 2048 + tid * 8;
                int r = e >> 6;
                int cs = (((tid & 7) ^ (r & 7)) * 8);
                gl16(wb + (size_t)(code0 + v0 + r) * KDIM + k0 + cs,
                     (void*)&Bsm[buf][i * 2048 + wv * 512]);
            }
        };

        // prologue: stage tiles 0 and 1; wait for tile 0 only (oldest 6 loads)
        STAGE(0, 0);
        STAGE(1, BKK);
        asm volatile("s_waitcnt vmcnt(6)" ::: "memory");
        __builtin_amdgcn_sched_barrier(0);
        __builtin_amdgcn_s_barrier();

        #pragma unroll
        for (int ks = 0; ks < NKS; ++ks) {
            const int cur = ks % 3;
            if (ks + 2 < NKS) STAGE((ks + 2) % 3, (ks + 2) * BKK);
            #pragma unroll
            for (int c = 0; c < 2; ++c) {        // BK=64 -> two MFMA-K chunks
                short8v a[2], b[4];
                #pragma unroll
                for (int m = 0; m < 2; ++m) {
                    int rowA = wm * 32 + m * 16 + l15;
                    a[m] = *(const short8v*)&Asm[cur][rowA * 64 + (((c * 4 + lhi) ^ (rowA & 7)) * 8)];
                }
                #pragma unroll
                for (int n = 0; n < 4; ++n) {
                    int rowB = wn * 64 + n * 16 + l15;
                    b[n] = *(const short8v*)&Bsm[cur][rowB * 64 + (((c * 4 + lhi) ^ (rowB & 7)) * 8)];
                }
                #pragma unroll
                for (int m = 0; m < 2; ++m)
                    #pragma unroll
                    for (int n = 0; n < 4; ++n)
                        acc[m][n] = __builtin_amdgcn_mfma_f32_16x16x32_bf16(a[m], b[n], acc[m][n], 0, 0, 0);
            }
            // wait: next tile (ks+1) staging complete; tile ks+2's 6 loads stay in flight
            if (ks + 2 < NKS) { asm volatile("s_waitcnt vmcnt(6)" ::: "memory"); }
            else              { asm volatile("s_waitcnt vmcnt(0)" ::: "memory"); }
            __builtin_amdgcn_sched_barrier(0);
            __builtin_amdgcn_s_barrier();
        }

        // ---- epilogue: d2' = ||w||^2 - 2 z.w ; per-token argmin ----
        const int ccolbase = code0 + v0 + wn * 64 + l15;
        float wn4[4];
        #pragma unroll
        for (int n = 0; n < 4; ++n) wn4[n] = wnorm[ccolbase + n * 16];

        #pragma unroll
        for (int m = 0; m < 2; ++m) {
            #pragma unroll
            for (int r = 0; r < 4; ++r) {
                float best = 3.4e38f; int bi = 0x7fffffff;
                #pragma unroll
                for (int n = 0; n < 4; ++n) {
                    float d = wn4[n] - 2.f * acc[m][n][r];
                    int ci = ccolbase + n * 16;
                    if (d < best) { best = d; bi = ci; }   // n ascending -> first-min
                }
                #pragma unroll
                for (int mk = 1; mk < 16; mk <<= 1) {
                    float ov = __shfl_xor(best, mk);
                    int   oi = __shfl_xor(bi, mk);
                    if (ov < best || (ov == best && oi < bi)) { best = ov; bi = oi; }
                }
                if (l15 == 0) {
                    int row = wm * 32 + m * 16 + lhi * 4 + r;
                    sV[wn][row] = best; sI[wn][row] = bi;
                }
            }
        }
        __syncthreads();
        if (tid < BMM) {
            float va = sV[0][tid]; int ia = sI[0][tid];
            float vb = sV[1][tid]; int ib = sI[1][tid];
            if (vb < va || (vb == va && ib < ia)) { va = vb; ia = ib; }
            if (va < runV[tid] || (va == runV[tid] && ia < runI[tid])) { runV[tid] = va; runI[tid] = ia; }
        }
        // next write to sV/sI is after the next N-tile's 9 barriers
    }

    if (tid < BMM) {
        sbV[slice * N_TOK + tok0 + tid] = runV[tid];
        sbI[slice * N_TOK + tok0 + tid] = runI[tid];
    }
}

// ---- merge 8 slice-results -> final index + histogram ----
__global__ __launch_bounds__(256) void vq_reduce(const float* __restrict__ sbV,
                                                 const int* __restrict__ sbI,
                                                 int* __restrict__ idx,
                                                 float* __restrict__ counts) {
    int t = blockIdx.x * 256 + threadIdx.x;
    float bv = sbV[t]; int bi = sbI[t];
    #pragma unroll
    for (int s = 1; s < SLICES; ++s) {
        float v = sbV[s * N_TOK + t];
        int   i = sbI[s * N_TOK + t];
        if (v < bv || (v == bv && i < bi)) { bv = v; bi = i; }
    }
    idx[t] = bi;
    atomicAdd(&counts[bi], 1.0f);
}

// ---- gather z_q (interleaved complex), block-reduced squared error ----
__global__ __launch_bounds__(256) void vq_gather(const float* __restrict__ zr,
                                                 const float* __restrict__ zi,
                                                 const float* __restrict__ w,
                                                 const int* __restrict__ idx,
                                                 float* __restrict__ out,
                                                 float* __restrict__ lossAcc,
                                                 int nTokOut) {
    const int lane = threadIdx.x & 63;
    const int wv = threadIdx.x >> 6;
    const int tokBase = blockIdx.x * 16 + wv * 4;
    float s = 0.f;
    for (int t = 0; t < 4; ++t) {
        int tok = tokBase + t;
        int bi = idx[tok];
        const float4* wre = (const float4*)(w + (size_t)bi * KDIM);
        const float4* wim = (const float4*)(w + (size_t)bi * KDIM + CDIM);
        const float4* ar4 = (const float4*)(zr + (size_t)tok * CDIM);
        const float4* ai4 = (const float4*)(zi + (size_t)tok * CDIM);
        float4 qr = wre[lane], qi = wim[lane], ar = ar4[lane], ai = ai4[lane];
        float d;
        d = qr.x - ar.x; s += d * d;  d = qr.y - ar.y; s += d * d;
        d = qr.z - ar.z; s += d * d;  d = qr.w - ar.w; s += d * d;
        d = qi.x - ai.x; s += d * d;  d = qi.y - ai.y; s += d * d;
        d = qi.z - ai.z; s += d * d;  d = qi.w - ai.w; s += d * d;
        if (tok < nTokOut) {
            float4 o0 = make_float4(qr.x, qi.x, qr.y, qi.y);
            float4 o1 = make_float4(qr.z, qi.z, qr.w, qi.w);
            float4* ob = (float4*)(out + (size_t)tok * 2 * CDIM);
            ob[lane * 2]     = o0;
            ob[lane * 2 + 1] = o1;
        }
    }
    #pragma unroll
    for (int off = 32; off > 0; off >>= 1) s += __shfl_down(s, off);
    __shared__ float ls[4];
    if (lane == 0) ls[wv] = s;
    __syncthreads();
    if (threadIdx.x == 0) atomicAdd(lossAcc, ls[0] + ls[1] + ls[2] + ls[3]);
}

__global__ __launch_bounds__(256) void vq_final(const float* __restrict__ counts,
                                                const float* __restrict__ lossAcc,
                                                float* __restrict__ scal) {
    __shared__ float red[256];
    float s = 0.f;
    for (int i = threadIdx.x; i < VOCAB; i += 256) {
        float p = counts[i] * (1.0f / 16384.0f);
        s += p * logf(p + 1e-10f);
    }
    red[threadIdx.x] = s;
    __syncthreads();
    for (int off = 128; off > 0; off >>= 1) {
        if (threadIdx.x < off) red[threadIdx.x] += red[threadIdx.x + off];
        __syncthreads();
    }
    if (threadIdx.x == 0) {
        scal[0] = lossAcc[0] * (1.25f / 8388608.0f);   // 1.25 * S / (N*2*CDIM)
        scal[1] = expf(-red[0]);
    }
}

extern "C" void kernel_launch(void* const* d_in, const int* in_sizes, int n_in,
                              void* d_out, int out_size, void* d_ws, size_t ws_size,
                              hipStream_t stream) {
    const float* zr = (const float*)d_in[0];
    const float* zi = (const float*)d_in[1];
    const float* w  = (const float*)d_in[2];
    float* out = (float*)d_out;
    float* fws = (float*)d_ws;

    // ws layout (float offsets; ~26.3 MB total)
    float* wnorm   = fws;                                  // [8192]
    float* counts  = fws + 8192;                           // [8192]
    float* lossAcc = fws + 16384;                          // [1] (+pad)
    int*   idx     = (int*)(fws + 16400);                  // [16384]
    float* sbV     = fws + 32784;                          // [8*16384]
    int*   sbI     = (int*)(fws + 163856);                 // [8*16384]
    unsigned short* zc = (unsigned short*)(fws + 294928);  // [16384*512] bf16
    unsigned short* wb = (unsigned short*)(fws + 294928 + 4194304); // [8192*512] bf16

    int nTokOut = (out_size - 2) / (2 * CDIM);
    if (nTokOut > N_TOK) nTokOut = N_TOK;

    vq_zconv<<<4096, 256, 0, stream>>>(zr, zi, zc);
    vq_wconv<<<2048, 256, 0, stream>>>(w, wb, wnorm, counts, lossAcc);
    vq_argmin_mfma<<<(N_TOK / BMM) * SLICES, 256, 0, stream>>>(zc, wb, wnorm, sbV, sbI);
    vq_reduce<<<N_TOK / 256, 256, 0, stream>>>(sbV, sbI, idx, counts);
    vq_gather<<<N_TOK / 16, 256, 0, stream>>>(zr, zi, w, idx, out, lossAcc, nTokOut);
    vq_final<<<1, 256, 0, stream>>>(counts, lossAcc, out + (out_size - 2));
}

// Round 13
// 391.346 us; speedup vs baseline: 8.5322x; 1.1108x over previous
//
#include <hip/hip_runtime.h>

#define N_TOK   16384
#define CDIM    256
#define KDIM    512
#define VOCAB   8192

#define SLICES  4
#define SL_V    (VOCAB / SLICES)   // 2048 codes per slice
#define BM      256                // tokens per block
#define BN      256                // codes per N-tile
#define BK      64                 // K per step
#define NKT     (KDIM / BK)        // 8 K-tiles

typedef __attribute__((ext_vector_type(8))) short short8v;
typedef __attribute__((ext_vector_type(4))) float f32x4;

typedef const __attribute__((address_space(1))) unsigned int* gp_t;
typedef __attribute__((address_space(3))) unsigned int* lp_t;
__device__ __forceinline__ void gl16(const void* g, void* l) {
    __builtin_amdgcn_global_load_lds((gp_t)g, (lp_t)l, 16, 0, 0);
}

__device__ __forceinline__ unsigned int bf2(float a, float b) {
    unsigned int ua = __float_as_uint(a); ua = (ua + 0x7FFF + ((ua >> 16) & 1)) >> 16;
    unsigned int ub = __float_as_uint(b); ub = (ub + 0x7FFF + ((ub >> 16) & 1)) >> 16;
    return (ub << 16) | ua;
}

// ---- z concat + fp32->bf16 convert: zc[tok][0:256]=re, [256:512]=im ----
__global__ __launch_bounds__(256) void vq_zconv(const float* __restrict__ zr,
                                                const float* __restrict__ zi,
                                                unsigned short* __restrict__ zc) {
    int t = blockIdx.x * 256 + threadIdx.x;
    int e = t * 8;
    int tok = e >> 9, c = e & 511;
    const float* src = (c < CDIM) ? (zr + (size_t)tok * CDIM + c)
                                  : (zi + (size_t)tok * CDIM + (c - CDIM));
    float4 x = ((const float4*)src)[0];
    float4 y = ((const float4*)src)[1];
    uint4 o = make_uint4(bf2(x.x, x.y), bf2(x.z, x.w), bf2(y.x, y.y), bf2(y.z, y.w));
    *(uint4*)(zc + e) = o;
}

// ---- w fp32->bf16 + exact fp32 ||w||^2, zero counts/lossAcc ----
__global__ __launch_bounds__(256) void vq_wconv(const float* __restrict__ w,
                                                unsigned short* __restrict__ wb,
                                                float* __restrict__ wnorm,
                                                float* __restrict__ counts,
                                                float* __restrict__ lossAcc) {
    int gid = blockIdx.x * 256 + threadIdx.x;
    int row = gid >> 6, l = gid & 63;
    const float* src = w + (size_t)row * KDIM + l * 8;
    float4 x = ((const float4*)src)[0];
    float4 y = ((const float4*)src)[1];
    float s = x.x*x.x + x.y*x.y + x.z*x.z + x.w*x.w
            + y.x*y.x + y.y*y.y + y.z*y.z + y.w*y.w;
    uint4 o = make_uint4(bf2(x.x, x.y), bf2(x.z, x.w), bf2(y.x, y.y), bf2(y.z, y.w));
    *(uint4*)(wb + (size_t)row * KDIM + l * 8) = o;
    #pragma unroll
    for (int off = 32; off > 0; off >>= 1) s += __shfl_down(s, off);
    if (l == 0) { wnorm[row] = s; counts[row] = 0.f; }
    if (gid == 0) *lossAcc = 0.f;
}

// ---- fused bf16-MFMA distance GEMM + argmin: 256x256 tile, 8 waves ----
// Structure per the proven 256-sq template: 512 thr (2M x 4N waves), BK=64,
// per-wave output 128x64 (acc[8][4] f32x4), dbuf LDS split in half-tiles,
// T2 XOR-swizzle via pre-swizzled global source (verified conflict->0 in r6),
// 4 setprio-wrapped MFMA phases (16 MFMA each) per K-tile, ONE barrier per
// K-tile (stage for kt+1 issues ~2400 cyc before the drain -> amortized).
// slice = blockIdx&3 -> each XCD's blocks share one 2MB codebook slice (L2).
__global__ __launch_bounds__(512, 2) void vq_argmin_mfma(const unsigned short* __restrict__ zc,
                                                         const unsigned short* __restrict__ wb,
                                                         const float* __restrict__ wnorm,
                                                         float* __restrict__ sbV,
                                                         int* __restrict__ sbI) {
    __shared__ unsigned short Ab[2][2][8192];   // [buf][half][row*64 + swz(col)]
    __shared__ unsigned short Bb[2][2][8192];
    __shared__ float sV[4][BM];
    __shared__ int   sI[4][BM];
    __shared__ float runV[BM];
    __shared__ int   runI[BM];

    const int tid = threadIdx.x;
    const int l   = tid & 63, w = tid >> 6;      // 8 waves
    const int wm  = w >> 2,  wn = w & 3;         // wave tile: rows wm*128, cols wn*64
    const int slice = blockIdx.x & (SLICES - 1);
    const int tok0  = (blockIdx.x >> 2) * BM;
    const int code0 = slice * SL_V;
    const int l15 = l & 15, lhi = l >> 4;
    const int bh = wn >> 1, brow0 = (wn & 1) * 64;   // B half / row base for this wave
    const int rstage = tid >> 3, sstage = tid & 7;

    for (int i = tid; i < BM; i += 512) { runV[i] = 3.4e38f; runI[i] = 0; }

    auto STAGE = [&](int buf, int k0, int v0) {
        #pragma unroll
        for (int h = 0; h < 2; ++h)
            #pragma unroll
            for (int i = 0; i < 2; ++i) {
                int r = i * 64 + rstage;                   // 0..127 within half
                int cs = (sstage ^ (r & 7)) * 8;           // swizzled 8-elem slot
                gl16(zc + (size_t)(tok0 + h * 128 + r) * KDIM + k0 + cs,
                     (void*)&Ab[buf][h][i * 4096 + (w << 9)]);
            }
        #pragma unroll
        for (int h = 0; h < 2; ++h)
            #pragma unroll
            for (int i = 0; i < 2; ++i) {
                int r = i * 64 + rstage;
                int cs = (sstage ^ (r & 7)) * 8;
                gl16(wb + (size_t)(code0 + v0 + h * 128 + r) * KDIM + k0 + cs,
                     (void*)&Bb[buf][h][i * 4096 + (w << 9)]);
            }
    };
    auto LDA = [&](int buf, int m, int c) -> short8v {
        int row = m * 16 + l15;
        return *(const short8v*)&Ab[buf][wm][row * 64 + (((c * 4 + lhi) ^ (row & 7)) * 8)];
    };
    auto LDB = [&](int buf, int n, int c) -> short8v {
        int row = brow0 + n * 16 + l15;
        return *(const short8v*)&Bb[buf][bh][row * 64 + (((c * 4 + lhi) ^ (row & 7)) * 8)];
    };

    for (int v0 = 0; v0 < SL_V; v0 += BN) {
        f32x4 acc[8][4] = {};
        if (v0 == 0) { STAGE(0, 0, 0); __syncthreads(); }

        int buf = 0;
        #pragma unroll 1
        for (int kt = 0; kt < NKT; ++kt) {
            if (kt < NKT - 1)        STAGE(buf ^ 1, (kt + 1) * BK, v0);
            else if (v0 + BN < SL_V) STAGE(buf ^ 1, 0, v0 + BN);

            short8v a[4][2], b[2][2];
            // P1: A m0-3 + B n0-1 -> acc[m][0..1]
            #pragma unroll
            for (int m = 0; m < 4; ++m) { a[m][0] = LDA(buf, m, 0); a[m][1] = LDA(buf, m, 1); }
            #pragma unroll
            for (int n = 0; n < 2; ++n) { b[n][0] = LDB(buf, n, 0); b[n][1] = LDB(buf, n, 1); }
            __builtin_amdgcn_s_setprio(1);
            #pragma unroll
            for (int m = 0; m < 4; ++m)
                #pragma unroll
                for (int n = 0; n < 2; ++n)
                    #pragma unroll
                    for (int c = 0; c < 2; ++c)
                        acc[m][n] = __builtin_amdgcn_mfma_f32_16x16x32_bf16(a[m][c], b[n][c], acc[m][n], 0, 0, 0);
            __builtin_amdgcn_s_setprio(0);
            // P2: B n2-3 -> acc[m][2..3]
            #pragma unroll
            for (int n = 0; n < 2; ++n) { b[n][0] = LDB(buf, n + 2, 0); b[n][1] = LDB(buf, n + 2, 1); }
            __builtin_amdgcn_s_setprio(1);
            #pragma unroll
            for (int m = 0; m < 4; ++m)
                #pragma unroll
                for (int n = 0; n < 2; ++n)
                    #pragma unroll
                    for (int c = 0; c < 2; ++c)
                        acc[m][n + 2] = __builtin_amdgcn_mfma_f32_16x16x32_bf16(a[m][c], b[n][c], acc[m][n + 2], 0, 0, 0);
            __builtin_amdgcn_s_setprio(0);
            // P3: A m4-7 -> acc[m+4][2..3] (B n2-3 still live)
            #pragma unroll
            for (int m = 0; m < 4; ++m) { a[m][0] = LDA(buf, m + 4, 0); a[m][1] = LDA(buf, m + 4, 1); }
            __builtin_amdgcn_s_setprio(1);
            #pragma unroll
            for (int m = 0; m < 4; ++m)
                #pragma unroll
                for (int n = 0; n < 2; ++n)
                    #pragma unroll
                    for (int c = 0; c < 2; ++c)
                        acc[m + 4][n + 2] = __builtin_amdgcn_mfma_f32_16x16x32_bf16(a[m][c], b[n][c], acc[m + 4][n + 2], 0, 0, 0);
            __builtin_amdgcn_s_setprio(0);
            // P4: B n0-1 (re-read) -> acc[m+4][0..1]
            #pragma unroll
            for (int n = 0; n < 2; ++n) { b[n][0] = LDB(buf, n, 0); b[n][1] = LDB(buf, n, 1); }
            __builtin_amdgcn_s_setprio(1);
            #pragma unroll
            for (int m = 0; m < 4; ++m)
                #pragma unroll
                for (int n = 0; n < 2; ++n)
                    #pragma unroll
                    for (int c = 0; c < 2; ++c)
                        acc[m + 4][n] = __builtin_amdgcn_mfma_f32_16x16x32_bf16(a[m][c], b[n][c], acc[m + 4][n], 0, 0, 0);
            __builtin_amdgcn_s_setprio(0);

            __syncthreads();   // drains vmcnt (next-tile staging) + lgkm; one per K-tile
            buf ^= 1;
        }

        // ---- epilogue: d2' = ||w||^2 - 2 z.w ; per-token argmin ----
        const int cb = code0 + v0 + wn * 64 + l15;
        float wn4[4];
        #pragma unroll
        for (int n = 0; n < 4; ++n) wn4[n] = wnorm[cb + n * 16];

        #pragma unroll
        for (int m = 0; m < 8; ++m) {
            #pragma unroll
            for (int j = 0; j < 4; ++j) {
                float best = 3.4e38f; int bi = 0x7fffffff;
                #pragma unroll
                for (int n = 0; n < 4; ++n) {
                    float d = wn4[n] - 2.f * acc[m][n][j];
                    if (d < best) { best = d; bi = cb + n * 16; }   // n ascending -> first-min
                }
                #pragma unroll
                for (int mk = 1; mk < 16; mk <<= 1) {
                    float ov = __shfl_xor(best, mk);
                    int   oi = __shfl_xor(bi, mk);
                    if (ov < best || (ov == best && oi < bi)) { best = ov; bi = oi; }
                }
                if (l15 == 0) {
                    int row = wm * 128 + m * 16 + lhi * 4 + j;
                    sV[wn][row] = best; sI[wn][row] = bi;
                }
            }
        }
        __syncthreads();
        if (tid < BM) {
            float bv = sV[0][tid]; int bi = sI[0][tid];
            #pragma unroll
            for (int s = 1; s < 4; ++s) {
                float v = sV[s][tid]; int i2 = sI[s][tid];
                if (v < bv || (v == bv && i2 < bi)) { bv = v; bi = i2; }
            }
            if (bv < runV[tid] || (bv == runV[tid] && bi < runI[tid])) { runV[tid] = bv; runI[tid] = bi; }
        }
        __syncthreads();   // WAR: sV reused next N-tile
    }

    if (tid < BM) {
        sbV[slice * N_TOK + tok0 + tid] = runV[tid];
        sbI[slice * N_TOK + tok0 + tid] = runI[tid];
    }
}

// ---- merge slice-results -> final index + histogram ----
__global__ __launch_bounds__(256) void vq_reduce(const float* __restrict__ sbV,
                                                 const int* __restrict__ sbI,
                                                 int* __restrict__ idx,
                                                 float* __restrict__ counts) {
    int t = blockIdx.x * 256 + threadIdx.x;
    float bv = sbV[t]; int bi = sbI[t];
    #pragma unroll
    for (int s = 1; s < SLICES; ++s) {
        float v = sbV[s * N_TOK + t];
        int   i = sbI[s * N_TOK + t];
        if (v < bv || (v == bv && i < bi)) { bv = v; bi = i; }
    }
    idx[t] = bi;
    atomicAdd(&counts[bi], 1.0f);
}

// ---- gather z_q (interleaved complex), block-reduced squared error ----
__global__ __launch_bounds__(256) void vq_gather(const float* __restrict__ zr,
                                                 const float* __restrict__ zi,
                                                 const float* __restrict__ w,
                                                 const int* __restrict__ idx,
                                                 float* __restrict__ out,
                                                 float* __restrict__ lossAcc,
                                                 int nTokOut) {
    const int lane = threadIdx.x & 63;
    const int wv = threadIdx.x >> 6;
    const int tokBase = blockIdx.x * 16 + wv * 4;
    float s = 0.f;
    for (int t = 0; t < 4; ++t) {
        int tok = tokBase + t;
        int bi = idx[tok];
        const float4* wre = (const float4*)(w + (size_t)bi * KDIM);
        const float4* wim = (const float4*)(w + (size_t)bi * KDIM + CDIM);
        const float4* ar4 = (const float4*)(zr + (size_t)tok * CDIM);
        const float4* ai4 = (const float4*)(zi + (size_t)tok * CDIM);
        float4 qr = wre[lane], qi = wim[lane], ar = ar4[lane], ai = ai4[lane];
        float d;
        d = qr.x - ar.x; s += d * d;  d = qr.y - ar.y; s += d * d;
        d = qr.z - ar.z; s += d * d;  d = qr.w - ar.w; s += d * d;
        d = qi.x - ai.x; s += d * d;  d = qi.y - ai.y; s += d * d;
        d = qi.z - ai.z; s += d * d;  d = qi.w - ai.w; s += d * d;
        if (tok < nTokOut) {
            float4 o0 = make_float4(qr.x, qi.x, qr.y, qi.y);
            float4 o1 = make_float4(qr.z, qi.z, qr.w, qi.w);
            float4* ob = (float4*)(out + (size_t)tok * 2 * CDIM);
            ob[lane * 2]     = o0;
            ob[lane * 2 + 1] = o1;
        }
    }
    #pragma unroll
    for (int off = 32; off > 0; off >>= 1) s += __shfl_down(s, off);
    __shared__ float ls[4];
    if (lane == 0) ls[wv] = s;
    __syncthreads();
    if (threadIdx.x == 0) atomicAdd(lossAcc, ls[0] + ls[1] + ls[2] + ls[3]);
}

__global__ __launch_bounds__(256) void vq_final(const float* __restrict__ counts,
                                                const float* __restrict__ lossAcc,
                                                float* __restrict__ scal) {
    __shared__ float red[256];
    float s = 0.f;
    for (int i = threadIdx.x; i < VOCAB; i += 256) {
        float p = counts[i] * (1.0f / 16384.0f);
        s += p * logf(p + 1e-10f);
    }
    red[threadIdx.x] = s;
    __syncthreads();
    for (int off = 128; off > 0; off >>= 1) {
        if (threadIdx.x < off) red[threadIdx.x] += red[threadIdx.x + off];
        __syncthreads();
    }
    if (threadIdx.x == 0) {
        scal[0] = lossAcc[0] * (1.25f / 8388608.0f);   // 1.25 * S / (N*2*CDIM)
        scal[1] = expf(-red[0]);
    }
}

extern "C" void kernel_launch(void* const* d_in, const int* in_sizes, int n_in,
                              void* d_out, int out_size, void* d_ws, size_t ws_size,
                              hipStream_t stream) {
    const float* zr = (const float*)d_in[0];
    const float* zi = (const float*)d_in[1];
    const float* w  = (const float*)d_in[2];
    float* out = (float*)d_out;
    float* fws = (float*)d_ws;

    float* wnorm   = fws;                                  // [8192]
    float* counts  = fws + 8192;                           // [8192]
    float* lossAcc = fws + 16384;                          // [1] (+pad)
    int*   idx     = (int*)(fws + 16400);                  // [16384]
    float* sbV     = fws + 32784;                          // [4*16384]
    int*   sbI     = (int*)(fws + 163856);                 // [4*16384]
    unsigned short* zc = (unsigned short*)(fws + 294928);  // [16384*512] bf16
    unsigned short* wb = (unsigned short*)(fws + 294928 + 4194304); // [8192*512] bf16

    int nTokOut = (out_size - 2) / (2 * CDIM);
    if (nTokOut > N_TOK) nTokOut = N_TOK;

    vq_zconv<<<4096, 256, 0, stream>>>(zr, zi, zc);
    vq_wconv<<<2048, 256, 0, stream>>>(w, wb, wnorm, counts, lossAcc);
    vq_argmin_mfma<<<(N_TOK / BM) * SLICES, 512, 0, stream>>>(zc, wb, wnorm, sbV, sbI);
    vq_reduce<<<N_TOK / 256, 256, 0, stream>>>(sbV, sbI, idx, counts);
    vq_gather<<<N_TOK / 16, 256, 0, stream>>>(zr, zi, w, idx, out, lossAcc, nTokOut);
    vq_final<<<1, 256, 0, stream>>>(counts, lossAcc, out + (out_size - 2));
}